// Round 1
// baseline (171.759 us; speedup 1.0000x reference)
//
#include <hip/hip_runtime.h>
#include <math.h>

#define VOCAB 100000
#define DIM   128
#define BATCH 16384
#define CMAX  10
#define KNEG  5
#define NSCORE (CMAX + KNEG)

// Numerically stable log(sigmoid(x)) = min(x,0) - log1p(exp(-|x|))
__device__ __forceinline__ float log_sigmoid(float x) {
    return fminf(x, 0.0f) - log1pf(expf(-fabsf(x)));
}

__global__ void zero_out_kernel(float* out) {
    if (threadIdx.x < 2) out[threadIdx.x] = 0.0f;
}

// One half-wave (32 lanes) per sample: 32 lanes x float4 = 512 B = one full
// embedding row per global_load_dwordx4. 256-thread block -> 8 samples/block.
__global__ __launch_bounds__(256) void sg_kernel(
    const int*   __restrict__ tgt,
    const int*   __restrict__ ctx,
    const int*   __restrict__ lens,
    const int*   __restrict__ neg,
    const float* __restrict__ in_emb,
    const float* __restrict__ out_emb,
    float*       __restrict__ out)
{
    const int tid  = threadIdx.x;
    const int lane = tid & 63;
    const int half = lane >> 5;       // which half-wave
    const int sub  = lane & 31;       // lane within half-wave
    const int waveInBlock = tid >> 6; // 0..3
    const int b = blockIdx.x * 8 + waveInBlock * 2 + half;   // sample index, always < BATCH

    // ---- gather target row (float4 per lane) ----
    const int t_word = tgt[b];
    const float4 tv = ((const float4*)(in_emb + (size_t)t_word * DIM))[sub];

    // ---- gather all 15 score words, issue all row loads up front ----
    int words[NSCORE];
#pragma unroll
    for (int c = 0; c < CMAX; ++c) words[c] = ctx[b * CMAX + c];
#pragma unroll
    for (int k = 0; k < KNEG; ++k) words[CMAX + k] = neg[b * KNEG + k];

    float part[NSCORE];
#pragma unroll
    for (int j = 0; j < NSCORE; ++j) {
        const float4 rv = ((const float4*)(out_emb + (size_t)words[j] * DIM))[sub];
        part[j] = tv.x * rv.x + tv.y * rv.y + tv.z * rv.z + tv.w * rv.w;
    }

    // ---- butterfly reduce each score across the 32 lanes of the half-wave ----
    // xor masks 16,8,4,2,1 never cross the half-wave boundary within a wave64.
#pragma unroll
    for (int j = 0; j < NSCORE; ++j) {
#pragma unroll
        for (int m = 16; m >= 1; m >>= 1)
            part[j] += __shfl_xor(part[j], m, 64);
    }

    // ---- per-sample loss terms (all 32 lanes hold identical scores) ----
    const int len = lens[b];
    float pos_acc = 0.0f;
#pragma unroll
    for (int c = 0; c < CMAX; ++c)
        if (c < len) pos_acc += log_sigmoid(part[c]);
    float neg_acc = 0.0f;
#pragma unroll
    for (int k = 0; k < KNEG; ++k)
        neg_acc += log_sigmoid(-part[CMAX + k]);

    float pos_per = 0.0f, neg_per = 0.0f;
    if (len > 0) {
        pos_per = -pos_acc / (float)len;
        neg_per = -neg_acc * (1.0f / KNEG);
    }

    // ---- block reduce (8 samples) then one atomic pair per block ----
    __shared__ float s_pos[8];
    __shared__ float s_neg[8];
    if (sub == 0) {
        const int slot = waveInBlock * 2 + half;
        s_pos[slot] = pos_per;
        s_neg[slot] = neg_per;
    }
    __syncthreads();
    if (tid == 0) {
        float ps = 0.0f, ns = 0.0f;
#pragma unroll
        for (int i = 0; i < 8; ++i) { ps += s_pos[i]; ns += s_neg[i]; }
        atomicAdd(&out[0], ps * (1.0f / BATCH));
        atomicAdd(&out[1], ns * (1.0f / BATCH));
    }
}

extern "C" void kernel_launch(void* const* d_in, const int* in_sizes, int n_in,
                              void* d_out, int out_size, void* d_ws, size_t ws_size,
                              hipStream_t stream) {
    const int*   tgt     = (const int*)  d_in[0];
    const int*   ctx     = (const int*)  d_in[1];
    const int*   lens    = (const int*)  d_in[2];
    const int*   neg     = (const int*)  d_in[3];
    const float* in_emb  = (const float*)d_in[4];
    const float* out_emb = (const float*)d_in[5];
    float* out = (float*)d_out;

    // d_out is re-poisoned to 0xAA before every timed launch -> zero it first.
    zero_out_kernel<<<1, 64, 0, stream>>>(out);
    sg_kernel<<<BATCH / 8, 256, 0, stream>>>(tgt, ctx, lens, neg, in_emb, out_emb, out);
}